// Round 5
// baseline (210.678 us; speedup 1.0000x reference)
//
#include <hip/hip_runtime.h>
#include <cstdint>
#include <cstddef>

#define NN 8192
#define ATOMF 64
#define HID 128
#define HEADS 8
#define NG 256
#define ELLW 192
#define NEGSLOPE 0.2f

// ---- build ELL edge list from dense adj (one HBM pass, values held in regs) ----
__global__ __launch_bounds__(256) void k_build_ell(const float* __restrict__ adj,
                                                   int* __restrict__ ell,
                                                   int* __restrict__ deg) {
    int row = blockIdx.x;
    int t = threadIdx.x;
    const float4* a4 = (const float4*)(adj + (size_t)row * NN);
    float4 v[8];
    int c = 0;
    #pragma unroll
    for (int it = 0; it < 8; ++it) {
        v[it] = a4[it * 256 + t];
        c += (v[it].x > 0.f) + (v[it].y > 0.f) + (v[it].z > 0.f) + (v[it].w > 0.f);
    }
    __shared__ int cnt[256];
    cnt[t] = c;
    __syncthreads();
    for (int off = 1; off < 256; off <<= 1) {
        int x = (t >= off) ? cnt[t - off] : 0;
        __syncthreads();
        cnt[t] += x;
        __syncthreads();
    }
    int pos = cnt[t] - c;          // exclusive prefix (deterministic order)
    int total = cnt[255];
    int* er = ell + (size_t)row * ELLW;
    #pragma unroll
    for (int it = 0; it < 8; ++it) {
        int j0 = (it * 256 + t) * 4;
        if (v[it].x > 0.f && pos < ELLW) { er[pos] = j0;     ++pos; }
        if (v[it].y > 0.f && pos < ELLW) { er[pos] = j0 + 1; ++pos; }
        if (v[it].z > 0.f && pos < ELLW) { er[pos] = j0 + 2; ++pos; }
        if (v[it].w > 0.f && pos < ELLW) { er[pos] = j0 + 3; ++pos; }
    }
    if (t == 0) deg[row] = total < ELLW ? total : ELLW;
}

// ---- reduce W1,W2 [1024,128] over their 8 row-blocks -> Wr [128,128] (fused) ----
__global__ __launch_bounds__(256) void k_wreduce(const float* __restrict__ W1,
                                                 const float* __restrict__ W2,
                                                 float* __restrict__ Wr1,
                                                 float* __restrict__ Wr2) {
    int b = blockIdx.x;
    const float* W = (b < 64) ? W1 : W2;
    float* Wr = (b < 64) ? Wr1 : Wr2;
    int i = (b & 63) * 256 + threadIdx.x;
    int k = i >> 7, c = i & 127;
    float s = 0.f;
    #pragma unroll
    for (int h = 0; h < HEADS; ++h)
        s += W[(size_t)(h * HID + k) * HID + c];
    Wr[i] = s;
}

// ---- Y[N,128] = act(X[N,K]) @ W[K,128] — register 4x4 micro-tile version ----
// Block: 32 rows x 128 cols; thread (rg,cg) owns rows 4rg..4rg+3, cols 4cg..4cg+3.
// Per k-quad: 4 ds_read_b128 of X (half-wave broadcast, conflict-free) +
// 4 global float4 of W (L1 broadcast) feed 64 FMAs. LDS instrs/thread: 128 (was 2048).
template<int K, bool RELU>
__global__ __launch_bounds__(256) void k_gemm(const float* __restrict__ X,
                                              const float* __restrict__ W,
                                              float* __restrict__ Y) {
    __shared__ float Xl[32 * K];
    int t = threadIdx.x;
    int row0 = blockIdx.x * 32;
    // stage X tile (vectorized, relu fused)
    const float4* Xg = (const float4*)(X + (size_t)row0 * K);
    float4* Xl4 = (float4*)Xl;
    #pragma unroll
    for (int i = t; i < 32 * K / 4; i += 256) {
        float4 v = Xg[i];
        if (RELU) {
            v.x = fmaxf(v.x, 0.f); v.y = fmaxf(v.y, 0.f);
            v.z = fmaxf(v.z, 0.f); v.w = fmaxf(v.w, 0.f);
        }
        Xl4[i] = v;
    }
    __syncthreads();
    int cg = t & 31, rg = t >> 5;
    int c0 = cg * 4;
    float acc[4][4];
    #pragma unroll
    for (int r = 0; r < 4; ++r)
        #pragma unroll
        for (int c = 0; c < 4; ++c) acc[r][c] = 0.f;
    for (int k = 0; k < K; k += 4) {
        float4 w0 = *(const float4*)(W + (size_t)(k + 0) * HID + c0);
        float4 w1 = *(const float4*)(W + (size_t)(k + 1) * HID + c0);
        float4 w2 = *(const float4*)(W + (size_t)(k + 2) * HID + c0);
        float4 w3 = *(const float4*)(W + (size_t)(k + 3) * HID + c0);
        #pragma unroll
        for (int r = 0; r < 4; ++r) {
            float4 xv = *(const float4*)(&Xl[(rg * 4 + r) * K + k]);   // b128, broadcast
            acc[r][0] += xv.x * w0.x + xv.y * w1.x + xv.z * w2.x + xv.w * w3.x;
            acc[r][1] += xv.x * w0.y + xv.y * w1.y + xv.z * w2.y + xv.w * w3.y;
            acc[r][2] += xv.x * w0.z + xv.y * w1.z + xv.z * w2.z + xv.w * w3.z;
            acc[r][3] += xv.x * w0.w + xv.y * w1.w + xv.z * w2.w + xv.w * w3.w;
        }
    }
    #pragma unroll
    for (int r = 0; r < 4; ++r)
        *(float4*)(Y + (size_t)(row0 + rg * 4 + r) * HID + c0) =
            make_float4(acc[r][0], acc[r][1], acc[r][2], acc[r][3]);
}

// ---- per-row attention scores ----
__global__ __launch_bounds__(256) void k_scores(const float* __restrict__ h,
                                                const float* __restrict__ asrc,
                                                const float* __restrict__ adst,
                                                float* __restrict__ ssrc,
                                                float* __restrict__ sdst) {
    int wid = threadIdx.x >> 6;
    int lane = threadIdx.x & 63;
    int row = blockIdx.x * 4 + wid;
    const float* hr = h + (size_t)row * HID;
    float h0 = hr[lane], h1 = hr[lane + 64];
    float ps = h0 * asrc[lane] + h1 * asrc[lane + 64];
    float pd = h0 * adst[lane] + h1 * adst[lane + 64];
    #pragma unroll
    for (int o = 32; o; o >>= 1) {
        ps += __shfl_xor(ps, o);
        pd += __shfl_xor(pd, o);
    }
    if (lane == 0) { ssrc[row] = ps; sdst[row] = pd; }
}

// ---- sparse masked softmax + aggregation. 4 rows/block, wave-per-row, no barriers. ----
__global__ __launch_bounds__(256, 6) void k_agg(const float* __restrict__ h,
                                                const float* __restrict__ ssrc,
                                                const float* __restrict__ sdst,
                                                const int* __restrict__ ell,
                                                const int* __restrict__ deg,
                                                float* __restrict__ out) {
    __shared__ float wls[4][ELLW];
    __shared__ int jls[4][ELLW];
    int wid = threadIdx.x >> 6;
    int l = threadIdx.x & 63;
    int row = blockIdx.x * 4 + wid;
    float* wl = wls[wid];
    int* jl = jls[wid];
    int d = deg[row];
    float si = ssrc[row];
    const int* er = ell + (size_t)row * ELLW;
    float m = -1e30f;
    for (int k = l; k < d; k += 64) {
        int j = er[k];
        float e = si + sdst[j];
        e = e > 0.f ? e : NEGSLOPE * e;
        jl[k] = j; wl[k] = e;
        m = fmaxf(m, e);
    }
    #pragma unroll
    for (int o = 32; o; o >>= 1) m = fmaxf(m, __shfl_xor(m, o));
    float s = 0.f;
    for (int k = l; k < d; k += 64) {
        float w = __expf(wl[k] - m);
        wl[k] = w;
        s += w;
    }
    #pragma unroll
    for (int o = 32; o; o >>= 1) s += __shfl_xor(s, o);
    float inv = 1.f / s;
    float a0 = 0.f, a1 = 0.f;
    const float* h2l = h + 2 * l;
    int k = 0;
    for (; k + 8 <= d; k += 8) {
        int j0 = jl[k],     j1 = jl[k + 1], j2 = jl[k + 2], j3 = jl[k + 3];
        int j4 = jl[k + 4], j5 = jl[k + 5], j6 = jl[k + 6], j7 = jl[k + 7];
        float w0 = wl[k],     w1 = wl[k + 1], w2 = wl[k + 2], w3 = wl[k + 3];
        float w4 = wl[k + 4], w5 = wl[k + 5], w6 = wl[k + 6], w7 = wl[k + 7];
        float2 v0 = *(const float2*)(h2l + (size_t)j0 * HID);
        float2 v1 = *(const float2*)(h2l + (size_t)j1 * HID);
        float2 v2 = *(const float2*)(h2l + (size_t)j2 * HID);
        float2 v3 = *(const float2*)(h2l + (size_t)j3 * HID);
        float2 v4 = *(const float2*)(h2l + (size_t)j4 * HID);
        float2 v5 = *(const float2*)(h2l + (size_t)j5 * HID);
        float2 v6 = *(const float2*)(h2l + (size_t)j6 * HID);
        float2 v7 = *(const float2*)(h2l + (size_t)j7 * HID);
        a0 += w0 * v0.x; a1 += w0 * v0.y;
        a0 += w1 * v1.x; a1 += w1 * v1.y;
        a0 += w2 * v2.x; a1 += w2 * v2.y;
        a0 += w3 * v3.x; a1 += w3 * v3.y;
        a0 += w4 * v4.x; a1 += w4 * v4.y;
        a0 += w5 * v5.x; a1 += w5 * v5.y;
        a0 += w6 * v6.x; a1 += w6 * v6.y;
        a0 += w7 * v7.x; a1 += w7 * v7.y;
    }
    for (; k < d; ++k) {
        int j = jl[k];
        float w = wl[k];
        float2 v = *(const float2*)(h2l + (size_t)j * HID);
        a0 += w * v.x; a1 += w * v.y;
    }
    float2 o2; o2.x = a0 * inv; o2.y = a1 * inv;
    *(float2*)(out + (size_t)row * HID + 2 * l) = o2;
}

// ---- pool + fc: one graph per wave (batch sorted), no atomics, deterministic ----
__global__ __launch_bounds__(256) void k_poolfc(const float* __restrict__ h,
                                                const int* __restrict__ batch,
                                                const float* __restrict__ fcw,
                                                const float* __restrict__ fcb,
                                                float* __restrict__ out) {
    int wid = threadIdx.x >> 6, l = threadIdx.x & 63;
    int g = blockIdx.x * 4 + wid;
    int lo = 0, hi = NN;
    while (lo < hi) { int mid = (lo + hi) >> 1; if (batch[mid] < g) lo = mid + 1; else hi = mid; }
    int e0 = lo;
    hi = NN;
    while (lo < hi) { int mid = (lo + hi) >> 1; if (batch[mid] <= g) lo = mid + 1; else hi = mid; }
    int e1 = lo;
    float sum = 0.f;
    for (int r = e0; r < e1; ++r) {
        const float* hr = h + (size_t)r * HID;
        sum += hr[l] * fcw[l] + hr[l + 64] * fcw[l + 64];
    }
    #pragma unroll
    for (int o = 32; o; o >>= 1) sum += __shfl_xor(sum, o);
    if (l == 0) out[g] = sum / fmaxf((float)(e1 - e0), 1.f) + fcb[0];
}

extern "C" void kernel_launch(void* const* d_in, const int* in_sizes, int n_in,
                              void* d_out, int out_size, void* d_ws, size_t ws_size,
                              hipStream_t stream) {
    const float* x    = (const float*)d_in[0];
    const float* adj  = (const float*)d_in[1];
    const int*   batch= (const int*)  d_in[2];
    const float* W0   = (const float*)d_in[3];
    const float* a0s  = (const float*)d_in[4];
    const float* a0d  = (const float*)d_in[5];
    const float* W1   = (const float*)d_in[6];
    const float* a1s  = (const float*)d_in[7];
    const float* a1d  = (const float*)d_in[8];
    const float* W2   = (const float*)d_in[9];
    const float* a2s  = (const float*)d_in[10];
    const float* a2d  = (const float*)d_in[11];
    const float* fcw  = (const float*)d_in[12];
    const float* fcb  = (const float*)d_in[13];
    float* out = (float*)d_out;

    char* ws = (char*)d_ws;
    size_t off = 0;
    auto alloc = [&](size_t bytes) {
        char* p = ws + off;
        off = (off + bytes + 255) & ~255UL;
        return p;
    };
    int*   ell  = (int*)  alloc((size_t)NN * ELLW * 4);   // 6.3 MB
    int*   deg  = (int*)  alloc((size_t)NN * 4);
    float* hA   = (float*)alloc((size_t)NN * HID * 4);    // 4 MB
    float* hB   = (float*)alloc((size_t)NN * HID * 4);    // 4 MB
    float* ssrc = (float*)alloc((size_t)NN * 4);
    float* sdst = (float*)alloc((size_t)NN * 4);
    float* Wr1  = (float*)alloc((size_t)HID * HID * 4);
    float* Wr2  = (float*)alloc((size_t)HID * HID * 4);
    (void)ws_size; (void)in_sizes; (void)n_in; (void)out_size;

    k_build_ell<<<NN, 256, 0, stream>>>(adj, ell, deg);
    k_wreduce<<<128, 256, 0, stream>>>(W1, W2, Wr1, Wr2);

    // layer 0
    k_gemm<ATOMF, false><<<NN / 32, 256, 0, stream>>>(x, W0, hA);
    k_scores<<<NN / 4, 256, 0, stream>>>(hA, a0s, a0d, ssrc, sdst);
    k_agg<<<NN / 4, 256, 0, stream>>>(hA, ssrc, sdst, ell, deg, hB);
    // layer 1 (tile+relu collapses to relu(h) @ Wr1)
    k_gemm<HID, true><<<NN / 32, 256, 0, stream>>>(hB, Wr1, hA);
    k_scores<<<NN / 4, 256, 0, stream>>>(hA, a1s, a1d, ssrc, sdst);
    k_agg<<<NN / 4, 256, 0, stream>>>(hA, ssrc, sdst, ell, deg, hB);
    // layer 2
    k_gemm<HID, true><<<NN / 32, 256, 0, stream>>>(hB, Wr2, hA);
    k_scores<<<NN / 4, 256, 0, stream>>>(hA, a2s, a2d, ssrc, sdst);
    k_agg<<<NN / 4, 256, 0, stream>>>(hA, ssrc, sdst, ell, deg, hB);

    // fused global mean pool + fc
    k_poolfc<<<NG / 4, 256, 0, stream>>>(hB, batch, fcw, fcb, out);
}